// Round 5
// baseline (65.741 us; speedup 1.0000x reference)
//
#include <hip/hip_runtime.h>
#include <math.h>

// BroadcastConv (max-plus conv): out[b,o,y,x] = max_{c,i,j} img[b,c,y+i-2,x+j-2] + kern[o,c,4-i,4-j]
// B=4, C=16, O=16, H=W=64, k=5x5, pad=2 with -inf.
//
// R5: single fused kernel (pad pass + extra graph node removed).
//  - lane = x over a full row: ONE coalesced dword load per row; neighbor
//    taps x+-1, x+-2 via __shfl (ds_bpermute, LDS pipe) instead of extra
//    VMEM -> 10 VMEM insts / 40 B per thread (R4: 20 insts / 200 B).
//  - y-edge rows: wave-uniform scalar branch skip (-inf rows contribute nothing).
//  - x-edge cols: 4 precomputed masks + 4 cndmasks per row, shared across o.
//  - weights on the scalar pipe (readfirstlane-uniform wave id).
//  - 512-thr blocks, 8 waves, c-split 8-way (2 c/wave), 1024 blocks
//    -> 32 waves/CU; cross-wave LDS max-reduce.

#define NEG_INF (-__builtin_inff())

__global__ __launch_bounds__(512, 8) void bconv_kernel(
        const float* __restrict__ img,
        const float* __restrict__ kern,
        float* __restrict__ out) {
    const int x  = threadIdx.x & 63;                                   // lane = W col
    const int w  = __builtin_amdgcn_readfirstlane(threadIdx.x >> 6);   // wave id 0..7, UNIFORM
    const int y  = blockIdx.x;
    const int og = blockIdx.y;
    const int b  = blockIdx.z;
    const int o0 = og * 4;
    const int c0 = w * 2;

    __shared__ float red[8][4][64];

    // Column-validity masks (lane-dependent, loop-invariant; live in sgpr pairs).
    const bool ok0 = (x >= 2);    // tap j=0 -> col x-2
    const bool ok1 = (x >= 1);    // tap j=1 -> col x-1
    const bool ok3 = (x <= 62);   // tap j=3 -> col x+1
    const bool ok4 = (x <= 61);   // tap j=4 -> col x+2

    float acc0 = NEG_INF, acc1 = NEG_INF, acc2 = NEG_INF, acc3 = NEG_INF;

#pragma unroll 1                  // two serial c-iterations: keep VGPRs small
    for (int cc = 0; cc < 2; ++cc) {
        const int c = c0 + cc;
        const float* __restrict__ pl = img + ((b * 16 + c) << 12);     // 64x64 plane
        const float* __restrict__ kp0 = kern + ((o0 + 0) * 16 + c) * 25;
        const float* __restrict__ kp1 = kern + ((o0 + 1) * 16 + c) * 25;
        const float* __restrict__ kp2 = kern + ((o0 + 2) * 16 + c) * 25;
        const float* __restrict__ kp3 = kern + ((o0 + 3) * 16 + c) * 25;

#pragma unroll
        for (int i = 0; i < 5; ++i) {
            const int yy = y + i - 2;
            if ((unsigned)yy >= 64u) continue;    // wave-uniform row skip
            // One coalesced load: lane x gets col x of row yy.
            float v2 = pl[(yy << 6) + x];
            // Neighbor taps via cross-lane exchange (index wraps &63; wrapped
            // lanes are exactly the masked-out ones).
            float v0 = __shfl(v2, x - 2);
            float v1 = __shfl(v2, x - 1);
            float v3 = __shfl(v2, x + 1);
            float v4 = __shfl(v2, x + 2);
            v0 = ok0 ? v0 : NEG_INF;
            v1 = ok1 ? v1 : NEG_INF;
            v3 = ok3 ? v3 : NEG_INF;
            v4 = ok4 ? v4 : NEG_INF;

            const int kb = 24 - 5 * i;            // weight idx for tap j is kb - j
#define ACC_O(kp, A)                                                     \
            {                                                            \
                float t0 = v0 + kp[kb - 0];                              \
                float t1 = v1 + kp[kb - 1];                              \
                float t2 = v2 + kp[kb - 2];                              \
                float t3 = v3 + kp[kb - 3];                              \
                float t4 = v4 + kp[kb - 4];                              \
                float m01  = fmaxf(t0, t1);                              \
                float m234 = fmaxf(fmaxf(t2, t3), t4);                   \
                A = fmaxf(A, fmaxf(m01, m234));                          \
            }
            ACC_O(kp0, acc0)
            ACC_O(kp1, acc1)
            ACC_O(kp2, acc2)
            ACC_O(kp3, acc3)
#undef ACC_O
        }
    }

    // Cross-wave max reduction (each wave covered 2 of 16 channels).
    red[w][0][x] = acc0;
    red[w][1][x] = acc1;
    red[w][2][x] = acc2;
    red[w][3][x] = acc3;
    __syncthreads();

    if (threadIdx.x < 256) {
        const int oo = threadIdx.x >> 6;
        float r = red[0][oo][x];
#pragma unroll
        for (int ww = 1; ww < 8; ++ww) r = fmaxf(r, red[ww][oo][x]);
        out[((b * 16 + o0 + oo) << 12) + (y << 6) + x] = r;
    }
}

extern "C" void kernel_launch(void* const* d_in, const int* in_sizes, int n_in,
                              void* d_out, int out_size, void* d_ws, size_t ws_size,
                              hipStream_t stream) {
    const float* img  = (const float*)d_in[0];   // (4,16,64,64)
    const float* kern = (const float*)d_in[1];   // (16,16,5,5)
    float* out = (float*)d_out;                  // (4,16,64,64)
    (void)in_sizes; (void)n_in; (void)out_size; (void)d_ws; (void)ws_size;

    dim3 grid(64, 4, 4);   // y, o/4, b -> 1024 blocks * 8 waves = 32 waves/CU
    hipLaunchKernelGGL(bconv_kernel, grid, dim3(512), 0, stream, img, kern, out);
}